// Round 4
// baseline (557.132 us; speedup 1.0000x reference)
//
#include <hip/hip_runtime.h>
#include <hip/hip_bf16.h>

// Cross-attention. Inputs fp32 (proven by R2->R3 NaN experiment; sniff kernel
// keeps a bf16 fallback). Output dtype follows input dtype: fp32 when flag=1.
// B=4 L=4096 R=512 DIM=1024 H=16 DH=64, scale = 1/8.
#define DIMC 1024
#define HEADS 16
#define DHEAD 64
#define LQ 4096
#define RK 512
#define BATCH 4

using bf16x8 = __attribute__((ext_vector_type(8))) __bf16;
using f32x4  = __attribute__((ext_vector_type(4))) float;

__device__ inline ushort f2bf(float f) {
  __hip_bfloat16 h = __float2bfloat16(f);
  return *reinterpret_cast<ushort*>(&h);
}

// ---------------- dtype sniff: count bf16-NaN/Inf patterns in Wq ------------
// fp32 data: even ushorts are mantissa junk -> ~32 hits expected in 16384.
// bf16 data (|w| < 1): exponent never 0xFF -> 0 hits.
__global__ __launch_bounds__(256) void sniff(const ushort* __restrict__ W,
                                             int* __restrict__ flag) {
  int cnt = 0;
  for (int i = threadIdx.x; i < 16384; i += 256) {
    ushort u = W[i];
    if ((u & 0x7F80u) == 0x7F80u) cnt++;
  }
  __shared__ int red[4];
  #pragma unroll
  for (int off = 32; off > 0; off >>= 1) cnt += __shfl_down(cnt, off, 64);
  if ((threadIdx.x & 63) == 0) red[threadIdx.x >> 6] = cnt;
  __syncthreads();
  if (threadIdx.x == 0) {
    int t = red[0] + red[1] + red[2] + red[3];
    *flag = (t >= 4) ? 1 : 0;
  }
}

// ---------------- weight transpose+convert: Wt[n][k] = bf16(W[k][n]) --------
__global__ __launch_bounds__(256) void transpose_w(const void* __restrict__ W0,
    const void* __restrict__ W1, const void* __restrict__ W2,
    const void* __restrict__ W3, ushort* __restrict__ D0,
    ushort* __restrict__ D1, ushort* __restrict__ D2, ushort* __restrict__ D3,
    const int* __restrict__ flagp) {
  __shared__ ushort tile[32][33];
  const int f32mode = *flagp;
  const void* src = (blockIdx.z == 0) ? W0 : (blockIdx.z == 1) ? W1
                  : (blockIdx.z == 2) ? W2 : W3;
  ushort* dst = (blockIdx.z == 0) ? D0 : (blockIdx.z == 1) ? D1
              : (blockIdx.z == 2) ? D2 : D3;
  const int tx = threadIdx.x, ty = threadIdx.y; // 32 x 8
  const int x = blockIdx.x * 32 + tx;
  if (f32mode) {
    const float* s32 = (const float*)src;
    #pragma unroll
    for (int j = 0; j < 32; j += 8)
      tile[ty + j][tx] = f2bf(s32[(size_t)(blockIdx.y * 32 + ty + j) * DIMC + x]);
  } else {
    const ushort* s16 = (const ushort*)src;
    #pragma unroll
    for (int j = 0; j < 32; j += 8)
      tile[ty + j][tx] = s16[(size_t)(blockIdx.y * 32 + ty + j) * DIMC + x];
  }
  __syncthreads();
  const int xo = blockIdx.y * 32 + tx;
  #pragma unroll
  for (int j = 0; j < 32; j += 8)
    dst[(size_t)(blockIdx.x * 32 + ty + j) * DIMC + xo] = tile[tx][ty + j];
}

// ---------------- GEMM: C[M][1024] = A[M][1024] @ Bt[1024][1024]^T -----------
// m97 structure. A fp32 (convert-on-stage) or bf16 (global_load_lds) per
// aflagp (nullptr = bf16). C fp32 or bf16 per oflagp (nullptr = bf16).
__global__ __launch_bounds__(256) void gemm_bt(const void* __restrict__ Av,
    const ushort* __restrict__ Bt, void* __restrict__ Cv,
    const int* __restrict__ aflagp, const int* __restrict__ oflagp) {
  __shared__ ushort As[128 * 32];
  __shared__ ushort Bs[128 * 32];
  const int tid  = threadIdx.x;
  const int wave = tid >> 6, lane = tid & 63;
  const int lr = lane & 15, quad = lane >> 4;
  const size_t m0 = (size_t)blockIdx.y * 128;
  const size_t n0 = (size_t)blockIdx.x * 128;
  const int wm = (wave >> 1) * 64, wn = (wave & 1) * 64;
  const int af32 = (aflagp != nullptr) ? *aflagp : 0;
  const int of32 = (oflagp != nullptr) ? *oflagp : 0;
  f32x4 acc[4][4] = {};
  for (int k0 = 0; k0 < DIMC; k0 += 32) {
    __syncthreads();
    // B staging: 16B async chunks, wave-uniform LDS base + lane*16
    #pragma unroll
    for (int t = 0; t < 2; ++t) {
      int c = (wave * 2 + t) * 64 + lane;   // [0,512) chunks of 8 bf16
      int row = c >> 2, cc = c & 3;
      const ushort* gb = Bt + (n0 + row) * DIMC + k0 + cc * 8;
      __builtin_amdgcn_global_load_lds(
          (__attribute__((address_space(1))) void*)gb,
          (__attribute__((address_space(3))) void*)(Bs + (size_t)(wave * 2 + t) * 512),
          16, 0, 0);
    }
    // A staging
    if (!af32) {
      const ushort* A = (const ushort*)Av;
      #pragma unroll
      for (int t = 0; t < 2; ++t) {
        int c = (wave * 2 + t) * 64 + lane;
        int row = c >> 2, cc = c & 3;
        const ushort* ga = A + (m0 + row) * DIMC + k0 + cc * 8;
        __builtin_amdgcn_global_load_lds(
            (__attribute__((address_space(1))) void*)ga,
            (__attribute__((address_space(3))) void*)(As + (size_t)(wave * 2 + t) * 512),
            16, 0, 0);
      }
    } else {
      const float* A32 = (const float*)Av;
      #pragma unroll
      for (int it = 0; it < 4; ++it) {
        int c2 = it * 256 + tid;            // [0,1024) chunks of 4 floats
        int row = c2 >> 3, cc4 = c2 & 7;
        float4 v = *(const float4*)(A32 + (m0 + row) * DIMC + k0 + cc4 * 4);
        ushort4 o4;
        o4.x = f2bf(v.x); o4.y = f2bf(v.y); o4.z = f2bf(v.z); o4.w = f2bf(v.w);
        *(ushort4*)(As + row * 32 + cc4 * 4) = o4;
      }
    }
    __syncthreads();
    bf16x8 af[4], bfr[4];
    #pragma unroll
    for (int mt = 0; mt < 4; ++mt)
      af[mt] = *(const bf16x8*)(As + (wm + mt * 16 + lr) * 32 + quad * 8);
    #pragma unroll
    for (int nt = 0; nt < 4; ++nt)
      bfr[nt] = *(const bf16x8*)(Bs + (wn + nt * 16 + lr) * 32 + quad * 8);
    #pragma unroll
    for (int mt = 0; mt < 4; ++mt)
      #pragma unroll
      for (int nt = 0; nt < 4; ++nt)
        acc[mt][nt] = __builtin_amdgcn_mfma_f32_16x16x32_bf16(
            af[mt], bfr[nt], acc[mt][nt], 0, 0, 0);
  }
  // C/D layout (m89): n = lane&15, m = quad*4 + reg
  if (of32) {
    float* C32 = (float*)Cv;
    #pragma unroll
    for (int mt = 0; mt < 4; ++mt)
      #pragma unroll
      for (int nt = 0; nt < 4; ++nt)
        #pragma unroll
        for (int j = 0; j < 4; ++j) {
          size_t m = m0 + wm + mt * 16 + quad * 4 + j;
          size_t n = n0 + wn + nt * 16 + lr;
          C32[m * DIMC + n] = acc[mt][nt][j];
        }
  } else {
    ushort* C16 = (ushort*)Cv;
    #pragma unroll
    for (int mt = 0; mt < 4; ++mt)
      #pragma unroll
      for (int nt = 0; nt < 4; ++nt)
        #pragma unroll
        for (int j = 0; j < 4; ++j) {
          size_t m = m0 + wm + mt * 16 + quad * 4 + j;
          size_t n = n0 + wn + nt * 16 + lr;
          C16[m * DIMC + n] = f2bf(acc[mt][nt][j]);
        }
  }
}

// ---------------- fused flash attention -------------------------------------
// grid (L/64, H, B); block 256 = 4 waves; wave w owns q rows [qb*64+w*16, +16).
// IN-PLACE over Q (block reads its own 64x64 Q region before its only writes).
__global__ __launch_bounds__(256) void attn(ushort* __restrict__ QO,
    const ushort* __restrict__ K, const ushort* __restrict__ V) {
  __shared__ ushort Ks[128 * 72];
  __shared__ ushort Vt[64 * 136];
  __shared__ ushort Pb[4 * 16 * 136];
  const int tid  = threadIdx.x;
  const int wave = tid >> 6, lane = tid & 63;
  const int lr = lane & 15, quad = lane >> 4;
  const int b = blockIdx.z, h = blockIdx.y, qb = blockIdx.x;

  bf16x8 aq[2];
  {
    size_t row = (size_t)b * LQ + qb * 64 + wave * 16 + lr;
    const ushort* qp = QO + row * DIMC + h * DHEAD + quad * 8;
    aq[0] = *(const bf16x8*)(qp);
    aq[1] = *(const bf16x8*)(qp + 32);
  }
  float mi[4] = {-1e30f, -1e30f, -1e30f, -1e30f};
  float li[4] = {};
  f32x4 o[4] = {};

  for (int rc = 0; rc < 4; ++rc) {
    __syncthreads();
    #pragma unroll
    for (int i = 0; i < 4; ++i) {
      int c = i * 256 + tid;          // 1024 chunks of 8 bf16
      int row = c >> 3, cc = c & 7;
      size_t gro = ((size_t)b * RK + rc * 128 + row) * DIMC + h * DHEAD + cc * 8;
      const uint4 kv = *(const uint4*)(K + gro);
      *(uint4*)(&Ks[row * 72 + cc * 8]) = kv;
      const uint4 vv = *(const uint4*)(V + gro);
      const ushort* vs = (const ushort*)&vv;
      #pragma unroll
      for (int d = 0; d < 8; ++d)
        Vt[(cc * 8 + d) * 136 + row] = vs[d];
    }
    __syncthreads();

    float s[8][4];
    #pragma unroll
    for (int nt = 0; nt < 8; ++nt) {
      f32x4 acc = {};
      const ushort* kp = Ks + (nt * 16 + lr) * 72 + quad * 8;
      acc = __builtin_amdgcn_mfma_f32_16x16x32_bf16(aq[0], *(const bf16x8*)kp,        acc, 0, 0, 0);
      acc = __builtin_amdgcn_mfma_f32_16x16x32_bf16(aq[1], *(const bf16x8*)(kp + 32), acc, 0, 0, 0);
      #pragma unroll
      for (int j = 0; j < 4; ++j) s[nt][j] = acc[j] * 0.125f;
    }

    float alpha[4];
    #pragma unroll
    for (int j = 0; j < 4; ++j) {
      float cm = s[0][j];
      #pragma unroll
      for (int nt = 1; nt < 8; ++nt) cm = fmaxf(cm, s[nt][j]);
      #pragma unroll
      for (int off = 8; off > 0; off >>= 1) cm = fmaxf(cm, __shfl_xor(cm, off, 16));
      float mnew = fmaxf(mi[j], cm);
      alpha[j] = __expf(mi[j] - mnew);
      mi[j] = mnew;
      float rs = 0.f;
      #pragma unroll
      for (int nt = 0; nt < 8; ++nt) {
        float p = __expf(s[nt][j] - mnew);
        s[nt][j] = p;
        rs += p;
      }
      #pragma unroll
      for (int off = 8; off > 0; off >>= 1) rs += __shfl_xor(rs, off, 16);
      li[j] = li[j] * alpha[j] + rs;
      #pragma unroll
      for (int n2 = 0; n2 < 4; ++n2) o[n2][j] *= alpha[j];
    }

    asm volatile("s_waitcnt lgkmcnt(0)" ::: "memory");
    ushort* pw = Pb + wave * 16 * 136;
    #pragma unroll
    for (int nt = 0; nt < 8; ++nt)
      #pragma unroll
      for (int j = 0; j < 4; ++j)
        pw[(quad * 4 + j) * 136 + nt * 16 + lr] = f2bf(s[nt][j]);
    asm volatile("s_waitcnt lgkmcnt(0)" ::: "memory");

    #pragma unroll
    for (int kt = 0; kt < 4; ++kt) {
      bf16x8 ap = *(const bf16x8*)(pw + lr * 136 + kt * 32 + quad * 8);
      #pragma unroll
      for (int n2 = 0; n2 < 4; ++n2) {
        bf16x8 bv = *(const bf16x8*)(Vt + (n2 * 16 + lr) * 136 + kt * 32 + quad * 8);
        o[n2] = __builtin_amdgcn_mfma_f32_16x16x32_bf16(ap, bv, o[n2], 0, 0, 0);
      }
    }
  }

  #pragma unroll
  for (int n2 = 0; n2 < 4; ++n2)
    #pragma unroll
    for (int j = 0; j < 4; ++j) {
      size_t row = (size_t)b * LQ + qb * 64 + wave * 16 + quad * 4 + j;
      QO[row * DIMC + h * DHEAD + n2 * 16 + lr] = f2bf(o[n2][j] / li[j]);
    }
}

// ---------------- launch -----------------------------------------------------
extern "C" void kernel_launch(void* const* d_in, const int* in_sizes, int n_in,
                              void* d_out, int out_size, void* d_ws, size_t ws_size,
                              hipStream_t stream) {
  ushort* outb = (ushort*)d_out;

  // Scratch hosted in d_out (all dead before final GEMM overwrites d_out):
  //   WqT | WkT | WvT | K | V  (7M ushorts = 14 MB; out buffer >= 33.5 MB)
  ushort* WqT = outb;
  ushort* WkT = outb + (size_t)1 * 1048576;
  ushort* WvT = outb + (size_t)2 * 1048576;
  ushort* Kw  = outb + (size_t)3 * 1048576;  // 2048*1024
  ushort* Vw  = outb + (size_t)5 * 1048576;  // 2048*1024

  // ws: Q/attnOut (in-place) | WoT | flag  (~35.7 MB)
  ushort* ws  = (ushort*)d_ws;
  ushort* Qw  = ws;                                   // 16384*1024
  ushort* WoT = ws + (size_t)16384 * 1024;            // 1024*1024
  int*  flag  = (int*)(ws + (size_t)16384 * 1024 + 1048576);

  sniff<<<1, 256, 0, stream>>>((const ushort*)d_in[2], flag);
  transpose_w<<<dim3(32, 32, 4), dim3(32, 8), 0, stream>>>(
      d_in[2], d_in[3], d_in[4], d_in[5], WqT, WkT, WvT, WoT, flag);
  gemm_bt<<<dim3(8, 128), 256, 0, stream>>>(d_in[0], WqT, Qw, flag, nullptr);
  gemm_bt<<<dim3(8, 16),  256, 0, stream>>>(d_in[1], WkT, Kw, flag, nullptr);
  gemm_bt<<<dim3(8, 16),  256, 0, stream>>>(d_in[1], WvT, Vw, flag, nullptr);
  attn<<<dim3(LQ / 64, HEADS, BATCH), 256, 0, stream>>>(Qw, Kw, Vw);
  // Output dtype follows input dtype: fp32 when flag==1, bf16 when flag==0.
  gemm_bt<<<dim3(8, 128), 256, 0, stream>>>(Qw, WoT, d_out, nullptr, flag);
}

// Round 5
// 371.935 us; speedup vs baseline: 1.4979x; 1.4979x over previous
//
#include <hip/hip_runtime.h>
#include <hip/hip_bf16.h>

// Cross-attention: fp32 in -> fp32 out (proven R3/R4), bf16 MFMA compute.
// B=4 L=4096 R=512 DIM=1024 H=16 DH=64, scale = 1/8.
#define DIMC 1024
#define HEADS 16
#define DHEAD 64
#define LQ 4096
#define RK 512
#define BATCH 4

using bf16x8  = __attribute__((ext_vector_type(8))) __bf16;
using short4v = __attribute__((ext_vector_type(4))) short;
using f32x4   = __attribute__((ext_vector_type(4))) float;

__device__ inline ushort f2bf(float f) {
  __hip_bfloat16 h = __float2bfloat16(f);
  return *reinterpret_cast<ushort*>(&h);
}

// ---------------- fp32 -> bf16 convert of x and ctx --------------------------
// x: 16777216 elems, ctx: 2097152 elems; 8 elems/thread, no tail.
__global__ __launch_bounds__(256) void cvt_in(const float* __restrict__ x,
    const float* __restrict__ ctx, ushort* __restrict__ xb,
    ushort* __restrict__ ctxb) {
  size_t i = ((size_t)blockIdx.x * 256 + threadIdx.x) * 8;
  const float* src; ushort* dst; size_t off;
  if (i < (size_t)16777216) { src = x; dst = xb; off = i; }
  else { src = ctx; dst = ctxb; off = i - 16777216; }
  float4 a = *(const float4*)(src + off);
  float4 b = *(const float4*)(src + off + 4);
  ushort u[8];
  u[0]=f2bf(a.x); u[1]=f2bf(a.y); u[2]=f2bf(a.z); u[3]=f2bf(a.w);
  u[4]=f2bf(b.x); u[5]=f2bf(b.y); u[6]=f2bf(b.z); u[7]=f2bf(b.w);
  *(uint4*)(dst + off) = *(const uint4*)u;
}

// ---------------- weight transpose+convert: Wt[n][k] = bf16(W[k][n]) ---------
__global__ __launch_bounds__(256) void transpose_w(const float* __restrict__ W0,
    const float* __restrict__ W1, const float* __restrict__ W2,
    const float* __restrict__ W3, ushort* __restrict__ D0,
    ushort* __restrict__ D1, ushort* __restrict__ D2, ushort* __restrict__ D3) {
  __shared__ ushort tile[32][33];
  const float* src = (blockIdx.z == 0) ? W0 : (blockIdx.z == 1) ? W1
                   : (blockIdx.z == 2) ? W2 : W3;
  ushort* dst = (blockIdx.z == 0) ? D0 : (blockIdx.z == 1) ? D1
              : (blockIdx.z == 2) ? D2 : D3;
  const int tx = threadIdx.x, ty = threadIdx.y; // 32 x 8
  const int x = blockIdx.x * 32 + tx;
  #pragma unroll
  for (int j = 0; j < 32; j += 8)
    tile[ty + j][tx] = f2bf(src[(size_t)(blockIdx.y * 32 + ty + j) * DIMC + x]);
  __syncthreads();
  const int xo = blockIdx.y * 32 + tx;
  #pragma unroll
  for (int j = 0; j < 32; j += 8)
    dst[(size_t)(blockIdx.x * 32 + ty + j) * DIMC + xo] = tile[tx][ty + j];
}

// ---------------- GEMM: C[M][1024..2048] = A @ Bt^T --------------------------
// m97 structure, A/Bt bf16 via global_load_lds w=16.
// mode 0: bf16 C.  mode 1: fp32 C.  mode 2 (KV): n<1024 -> bf16 K into C;
// n>=1024 -> V written transposed per (b,h): CV[((b*16+h)*64+dh)*512 + r].
__global__ __launch_bounds__(256) void gemm_bt(const ushort* __restrict__ A,
    const ushort* __restrict__ Bt, void* __restrict__ Cv,
    ushort* __restrict__ CV, int mode) {
  __shared__ ushort As[128 * 32];
  __shared__ ushort Bs[128 * 32];
  const int tid  = threadIdx.x;
  const int wave = tid >> 6, lane = tid & 63;
  const int lr = lane & 15, quad = lane >> 4;
  const size_t m0 = (size_t)blockIdx.y * 128;
  const size_t n0 = (size_t)blockIdx.x * 128;
  const int wm = (wave >> 1) * 64, wn = (wave & 1) * 64;
  f32x4 acc[4][4] = {};
  for (int k0 = 0; k0 < DIMC; k0 += 32) {
    __syncthreads();
    #pragma unroll
    for (int t = 0; t < 2; ++t) {
      int c = (wave * 2 + t) * 64 + lane;   // [0,512) chunks of 8 bf16
      int row = c >> 2, cc = c & 3;
      const ushort* ga = A  + (m0 + row) * DIMC + k0 + cc * 8;
      const ushort* gb = Bt + (n0 + row) * DIMC + k0 + cc * 8;
      __builtin_amdgcn_global_load_lds(
          (__attribute__((address_space(1))) void*)ga,
          (__attribute__((address_space(3))) void*)(As + (size_t)(wave * 2 + t) * 512),
          16, 0, 0);
      __builtin_amdgcn_global_load_lds(
          (__attribute__((address_space(1))) void*)gb,
          (__attribute__((address_space(3))) void*)(Bs + (size_t)(wave * 2 + t) * 512),
          16, 0, 0);
    }
    __syncthreads();
    bf16x8 af[4], bfr[4];
    #pragma unroll
    for (int mt = 0; mt < 4; ++mt)
      af[mt] = *(const bf16x8*)(As + (wm + mt * 16 + lr) * 32 + quad * 8);
    #pragma unroll
    for (int nt = 0; nt < 4; ++nt)
      bfr[nt] = *(const bf16x8*)(Bs + (wn + nt * 16 + lr) * 32 + quad * 8);
    #pragma unroll
    for (int mt = 0; mt < 4; ++mt)
      #pragma unroll
      for (int nt = 0; nt < 4; ++nt)
        acc[mt][nt] = __builtin_amdgcn_mfma_f32_16x16x32_bf16(
            af[mt], bfr[nt], acc[mt][nt], 0, 0, 0);
  }
  // C/D layout: n = lane&15, m = quad*4 + reg
  if (mode == 1) {
    float* C32 = (float*)Cv;
    #pragma unroll
    for (int mt = 0; mt < 4; ++mt)
      #pragma unroll
      for (int nt = 0; nt < 4; ++nt)
        #pragma unroll
        for (int j = 0; j < 4; ++j) {
          size_t m = m0 + wm + mt * 16 + quad * 4 + j;
          size_t n = n0 + wn + nt * 16 + lr;
          C32[m * DIMC + n] = acc[mt][nt][j];
        }
  } else if (mode == 0 || n0 < 1024) {
    ushort* C16 = (ushort*)Cv;
    #pragma unroll
    for (int mt = 0; mt < 4; ++mt)
      #pragma unroll
      for (int nt = 0; nt < 4; ++nt)
        #pragma unroll
        for (int j = 0; j < 4; ++j) {
          size_t m = m0 + wm + mt * 16 + quad * 4 + j;
          size_t n = n0 + wn + nt * 16 + lr;
          C16[m * DIMC + n] = f2bf(acc[mt][nt][j]);
        }
  } else {
    // V half: write transposed V^T[b][h][dh][r]
    #pragma unroll
    for (int mt = 0; mt < 4; ++mt)
      #pragma unroll
      for (int nt = 0; nt < 4; ++nt) {
        size_t m = m0 + wm + mt * 16 + quad * 4;       // r base (4-aligned)
        int hcol = (int)(n0 + wn + nt * 16 + lr) - 1024;
        int h = hcol >> 6, dh = hcol & 63;
        int bb = (int)(m >> 9), r = (int)(m & 511);
        ushort o4[4];
        #pragma unroll
        for (int j = 0; j < 4; ++j) o4[j] = f2bf(acc[mt][nt][j]);
        *(ushort4*)(CV + (((size_t)bb * HEADS + h) * 64 + dh) * RK + r) =
            *(const ushort4*)o4;
      }
  }
}

// ---------------- fused flash attention (S^T trick) --------------------------
// grid (64, 16, 4) = (qb, h, b); block 256 = 4 waves; wave owns 16 q-rows
// (q = lane&15). S^T = mfma32(A=K, B=Q) -> C-regs ARE the x16 A-fragment for
// P*V via mfma_f32_16x16x16bf16_1k: no P LDS round-trip. V pre-transposed in
// global (V^T[b][h][dh][r]). In-place output over Q.
__global__ __launch_bounds__(256) void attn(ushort* __restrict__ QO,
    const ushort* __restrict__ K, const ushort* __restrict__ Vt) {
  __shared__ __align__(16) ushort Ks[128 * 72];
  __shared__ __align__(16) ushort Vs[64 * 136];
  const int tid  = threadIdx.x;
  const int wave = tid >> 6, lane = tid & 63;
  const int lr = lane & 15, quad = lane >> 4;
  const int b = blockIdx.z, h = blockIdx.y, qb = blockIdx.x;

  // Q B-fragment: B[n=q=lane&15][k=d=quad*8+j]
  bf16x8 bq[2];
  {
    size_t row = (size_t)b * LQ + qb * 64 + wave * 16 + lr;
    const ushort* qp = QO + row * DIMC + h * DHEAD + quad * 8;
    bq[0] = *(const bf16x8*)(qp);
    bq[1] = *(const bf16x8*)(qp + 32);
  }
  float mi = -1e30f, li = 0.f;
  f32x4 o[4] = {};   // O[q=quad*4+j][dh=n2*16+lr]

  for (int rc = 0; rc < 4; ++rc) {
    __syncthreads();
    #pragma unroll
    for (int i = 0; i < 4; ++i) {
      int c = i * 256 + tid;
      { // K chunk: 128 rows x 64, 8x16B chunks/row -> Ks[r][72]
        int kr = c >> 3, kc = c & 7;
        *(uint4*)(Ks + kr * 72 + kc * 8) = *(const uint4*)(
            K + ((size_t)b * RK + rc * 128 + kr) * DIMC + h * DHEAD + kc * 8);
      }
      { // V^T chunk: 64 rows(dh) x 128(r), 16x16B chunks/row -> Vs[dh][136]
        int vr = c >> 4, vc = c & 15;
        *(uint4*)(Vs + vr * 136 + vc * 8) = *(const uint4*)(
            Vt + (((size_t)b * HEADS + h) * 64 + vr) * RK + rc * 128 + vc * 8);
      }
    }
    __syncthreads();

    // S^T = K Q^T : 8 r-tiles; C-regs: S^T[r=nt*16+quad*4+j][q=lr]
    float s[8][4];
    #pragma unroll
    for (int nt = 0; nt < 8; ++nt) {
      f32x4 acc = {};
      const ushort* kp = Ks + (nt * 16 + lr) * 72 + quad * 8;
      acc = __builtin_amdgcn_mfma_f32_16x16x32_bf16(*(const bf16x8*)kp,        bq[0], acc, 0, 0, 0);
      acc = __builtin_amdgcn_mfma_f32_16x16x32_bf16(*(const bf16x8*)(kp + 32), bq[1], acc, 0, 0, 0);
      #pragma unroll
      for (int j = 0; j < 4; ++j) s[nt][j] = acc[j] * 0.125f;
    }

    // online softmax: one q-row per lane (replicated across the 4 quads)
    float cm = s[0][0];
    #pragma unroll
    for (int nt = 0; nt < 8; ++nt)
      #pragma unroll
      for (int j = 0; j < 4; ++j) cm = fmaxf(cm, s[nt][j]);
    cm = fmaxf(cm, __shfl_xor(cm, 16));
    cm = fmaxf(cm, __shfl_xor(cm, 32));
    float mnew = fmaxf(mi, cm);
    float alpha = __expf(mi - mnew);
    mi = mnew;
    float rs = 0.f;
    #pragma unroll
    for (int nt = 0; nt < 8; ++nt)
      #pragma unroll
      for (int j = 0; j < 4; ++j) {
        float p = __expf(s[nt][j] - mnew);
        s[nt][j] = p;
        rs += p;
      }
    rs += __shfl_xor(rs, 16);
    rs += __shfl_xor(rs, 32);
    li = li * alpha + rs;

    // rescale O by alpha of its own row q=quad*4+j
    float a_bc[4];
    #pragma unroll
    for (int j = 0; j < 4; ++j) a_bc[j] = __shfl(alpha, quad * 4 + j, 16);
    #pragma unroll
    for (int n2 = 0; n2 < 4; ++n2)
      #pragma unroll
      for (int j = 0; j < 4; ++j) o[n2][j] *= a_bc[j];

    // P regs -> bf16 x16-A-fragments (tile kt: r=kt*16+quad*4+j, m=q=lr)
    short4v pf[8];
    #pragma unroll
    for (int nt = 0; nt < 8; ++nt)
      #pragma unroll
      for (int j = 0; j < 4; ++j) pf[nt][j] = (short)f2bf(s[nt][j]);

    // O += P V : 8 k-steps of 16 x 4 dh-tiles, V^T B-frag from LDS (b64)
    #pragma unroll
    for (int kt = 0; kt < 8; ++kt)
      #pragma unroll
      for (int n2 = 0; n2 < 4; ++n2) {
        short4v bv = *(const short4v*)(Vs + (n2 * 16 + lr) * 136 + kt * 16 + quad * 4);
        o[n2] = __builtin_amdgcn_mfma_f32_16x16x16bf16_1k(pf[kt], bv, o[n2], 0, 0, 0);
      }
  }

  // normalize + write in-place; row q = quad*4+j needs li from lane q
  float li_bc[4];
  #pragma unroll
  for (int j = 0; j < 4; ++j) li_bc[j] = __shfl(li, quad * 4 + j, 16);
  #pragma unroll
  for (int n2 = 0; n2 < 4; ++n2)
    #pragma unroll
    for (int j = 0; j < 4; ++j) {
      size_t row = (size_t)b * LQ + qb * 64 + wave * 16 + quad * 4 + j;
      QO[row * DIMC + h * DHEAD + n2 * 16 + lr] = f2bf(o[n2][j] / li_bc[j]);
    }
}

// ---------------- launch -----------------------------------------------------
extern "C" void kernel_launch(void* const* d_in, const int* in_sizes, int n_in,
                              void* d_out, int out_size, void* d_ws, size_t ws_size,
                              hipStream_t stream) {
  const float* x   = (const float*)d_in[0];
  const float* ctx = (const float*)d_in[1];

  // d_out scratch (fp32 out buffer = 67 MB; all dead before final GEMM):
  // xb | ctxb | WqT | WkT | WvT | Kw | Vt_g  = 52.4 MB
  ushort* outs = (ushort*)d_out;
  ushort* xb   = outs;                               // 16777216
  ushort* ctxb = outs + (size_t)16777216;            //  2097152
  ushort* WqT  = outs + (size_t)18874368;            //  1048576
  ushort* WkT  = outs + (size_t)19922944;            //  1048576 (WvT contiguous)
  ushort* WvT  = outs + (size_t)20971520;            //  1048576
  ushort* Kw   = outs + (size_t)22020096;            //  2097152
  ushort* Vt_g = outs + (size_t)24117248;            //  2097152

  // ws: Qw (33.5 MB) | WoT (2.1 MB)  -- same footprint proven in R3/R4
  ushort* ws  = (ushort*)d_ws;
  ushort* Qw  = ws;
  ushort* WoT = ws + (size_t)16384 * 1024;

  cvt_in<<<9216, 256, 0, stream>>>(x, ctx, xb, ctxb);
  transpose_w<<<dim3(32, 32, 4), dim3(32, 8), 0, stream>>>(
      (const float*)d_in[2], (const float*)d_in[3], (const float*)d_in[4],
      (const float*)d_in[5], WqT, WkT, WvT, WoT);
  gemm_bt<<<dim3(8, 128), 256, 0, stream>>>(xb,   WqT, Qw, nullptr, 0);
  gemm_bt<<<dim3(16, 16), 256, 0, stream>>>(ctxb, WkT, Kw, Vt_g,    2);
  attn<<<dim3(LQ / 64, HEADS, BATCH), 256, 0, stream>>>(Qw, Kw, Vt_g);
  gemm_bt<<<dim3(8, 128), 256, 0, stream>>>(Qw, WoT, d_out, nullptr, 1);
}